// Round 2
// baseline (1489.596 us; speedup 1.0000x reference)
//
#include <hip/hip_runtime.h>
#include <stdint.h>

#define N_TOK 8192
#define DDIM 2048
#define IDIM 6144
#define NEXP 8
#define RLORA 32

typedef __attribute__((ext_vector_type(8))) short short8;
typedef __attribute__((ext_vector_type(4))) float floatx4;
typedef __attribute__((ext_vector_type(4))) unsigned short ushortx4;

__device__ __forceinline__ unsigned short f2bf(float f) {
  union { float f; unsigned u; } v; v.f = f;
  unsigned u = v.u;
  unsigned r = (u + 0x7fffu + ((u >> 16) & 1u)) >> 16;
  return (unsigned short)r;
}

__device__ __forceinline__ void gload_lds16(const void* g, void* l) {
  __builtin_amdgcn_global_load_lds(
      (const __attribute__((address_space(1))) void*)g,
      (__attribute__((address_space(3))) void*)l, 16, 0, 0);
}

// ---------------- router + x->bf16 convert (one wave per token) ----------------
__global__ __launch_bounds__(256) void router_kernel(
    const float* __restrict__ x, const float* __restrict__ rw,
    unsigned short* __restrict__ xb, float* __restrict__ logits_out,
    int* __restrict__ idx) {
  int wave = threadIdx.x >> 6, lane = threadIdx.x & 63;
  int n = blockIdx.x * 4 + wave;
  const float* xr = x + (size_t)n * DDIM;
  unsigned short* xbr = xb + (size_t)n * DDIM;
  float acc[NEXP];
#pragma unroll
  for (int e = 0; e < NEXP; e++) acc[e] = 0.f;
#pragma unroll
  for (int j = 0; j < 8; j++) {
    int d = j * 256 + lane * 4;
    floatx4 v = *(const floatx4*)(xr + d);
    ushortx4 s;
    s[0] = f2bf(v[0]); s[1] = f2bf(v[1]); s[2] = f2bf(v[2]); s[3] = f2bf(v[3]);
    *(ushortx4*)(xbr + d) = s;
    const float* rwd = rw + (size_t)d * NEXP;
#pragma unroll
    for (int t = 0; t < 4; t++) {
      float xv = v[t];
      const float* rr = rwd + t * NEXP;
#pragma unroll
      for (int e = 0; e < NEXP; e++) acc[e] += xv * rr[e];
    }
  }
#pragma unroll
  for (int off = 32; off > 0; off >>= 1) {
#pragma unroll
    for (int e = 0; e < NEXP; e++) acc[e] += __shfl_xor(acc[e], off, 64);
  }
  if (lane == 0) {
    float best = acc[0]; int bi = 0;
#pragma unroll
    for (int e = 1; e < NEXP; e++)
      if (acc[e] > best) { best = acc[e]; bi = e; }
    idx[n] = bi;
#pragma unroll
    for (int e = 0; e < NEXP; e++) logits_out[(size_t)n * NEXP + e] = acc[e];
  }
}

// ---------------- fp32 [Rr][Cc] -> bf16 [Cc][Rr] transpose ----------------
__global__ __launch_bounds__(256) void transpose_w_kernel(
    const float* __restrict__ in, unsigned short* __restrict__ out, int Rr, int Cc) {
  __shared__ float lds[32][33];
  int r0 = blockIdx.y * 32, c0 = blockIdx.x * 32;
  int tx = threadIdx.x & 31, ty = threadIdx.x >> 5;
#pragma unroll
  for (int k = 0; k < 4; k++) {
    int r = ty + k * 8;
    lds[r][tx] = in[(size_t)(r0 + r) * Cc + c0 + tx];
  }
  __syncthreads();
#pragma unroll
  for (int k = 0; k < 4; k++) {
    int cc = ty + k * 8;
    out[(size_t)(c0 + cc) * Rr + r0 + tx] = f2bf(lds[tx][cc]);
  }
}

// ---------------- pack A_gate/A_up -> aat[512][2048] bf16 (col = h*256+e*32+r) ----------------
__global__ __launch_bounds__(256) void pack_a_kernel(
    const float* __restrict__ Ag, const float* __restrict__ Au,
    unsigned short* __restrict__ aat) {
  int o = blockIdx.x * 256 + threadIdx.x;    // [0, 2^20)
  int h = o >> 19;
  int oo = o & ((1 << 19) - 1);
  int c = oo >> 11, d = oo & 2047;           // c in [0,256)
  int e = c >> 5, r = c & 31;
  const float* src = h ? Au : Ag;
  float v = src[(e << 16) + (d << 5) + r];   // A[e][d][r]
  aat[(size_t)(h * 256 + c) * DDIM + d] = f2bf(v);
}

// ---------------- B[e][R][I] fp32 -> Bt[e][I][R] bf16 ----------------
__global__ __launch_bounds__(256) void transpose_b_kernel(
    const float* __restrict__ Bg, const float* __restrict__ Bu,
    unsigned short* __restrict__ btg, unsigned short* __restrict__ btu) {
  __shared__ float lds[32][33];
  int i0 = blockIdx.x * 32, e = blockIdx.y;
  const float* in = blockIdx.z ? Bu : Bg;
  unsigned short* out = blockIdx.z ? btu : btg;
  int tx = threadIdx.x & 31, ty = threadIdx.x >> 5;
#pragma unroll
  for (int k = 0; k < 4; k++) {
    int r = ty + k * 8;
    lds[r][tx] = in[((size_t)e * RLORA + r) * IDIM + i0 + tx];
  }
  __syncthreads();
#pragma unroll
  for (int k = 0; k < 4; k++) {
    int ii = ty + k * 8;
    out[((size_t)e * IDIM + i0 + ii) * RLORA + tx] = f2bf(lds[tx][ii]);
  }
}

// ---------------- single-output GEMM main loop (for T and down) ----------------
__device__ __forceinline__ void mm_main(const unsigned short* __restrict__ Ab,
                                        const unsigned short* __restrict__ Bb,
                                        int K, int row0, int col0,
                                        unsigned short* sA, unsigned short* sB,
                                        floatx4* acc) {
  const int tid = threadIdx.x;
  const int wave = tid >> 6, lane = tid & 63;
  const int wr = wave >> 1, wc = wave & 1;
  const int q = lane >> 4, m16 = lane & 15;
  for (int k0 = 0; k0 < K; k0 += 32) {
    __syncthreads();
#pragma unroll
    for (int rr = 0; rr < 2; rr++) {
      int e = tid * 8 + rr * 2048;
      int r = e >> 5, kk = e & 31;
      gload_lds16(Ab + (size_t)(row0 + r) * K + (k0 + kk), sA + e);
      gload_lds16(Bb + (size_t)(col0 + r) * K + (k0 + kk), sB + e);
    }
    __syncthreads();
    short8 a[4], b[4];
#pragma unroll
    for (int m = 0; m < 4; m++)
      a[m] = *(const short8*)(sA + (wr * 64 + m * 16 + m16) * 32 + q * 8);
#pragma unroll
    for (int n = 0; n < 4; n++)
      b[n] = *(const short8*)(sB + (wc * 64 + n * 16 + m16) * 32 + q * 8);
#pragma unroll
    for (int m = 0; m < 4; m++)
#pragma unroll
      for (int n = 0; n < 4; n++)
        acc[m * 4 + n] = __builtin_amdgcn_mfma_f32_16x16x32_bf16(a[m], b[n], acc[m * 4 + n], 0, 0, 0);
  }
}

// ---------------- small GEMM: T = x @ packedA  (K=2048, N=512) ----------------
__global__ __launch_bounds__(256) void gemm_t_kernel(
    const unsigned short* __restrict__ xb, const unsigned short* __restrict__ aat,
    unsigned short* __restrict__ Tm) {
  __shared__ __align__(16) unsigned short sA[4096], sB[4096];
  floatx4 acc[16];
#pragma unroll
  for (int i = 0; i < 16; i++)
#pragma unroll
    for (int j = 0; j < 4; j++) acc[i][j] = 0.f;
  int row0 = blockIdx.y * 128, col0 = blockIdx.x * 128;
  mm_main(xb, aat, DDIM, row0, col0, sA, sB, acc);
  const int wave = threadIdx.x >> 6, lane = threadIdx.x & 63;
  const int wr = wave >> 1, wc = wave & 1;
  const int q = lane >> 4, m16 = lane & 15;
#pragma unroll
  for (int m = 0; m < 4; m++)
#pragma unroll
    for (int n = 0; n < 4; n++)
#pragma unroll
      for (int r = 0; r < 4; r++) {
        int grow = row0 + wr * 64 + m * 16 + q * 4 + r;
        int gcol = col0 + wc * 64 + n * 16 + m16;
        Tm[(size_t)grow * 512 + gcol] = f2bf(acc[m * 4 + n][r]);
      }
}

// ---------------- fused gate+up+LoRA+SwiGLU kernel ----------------
// One 128x128 tile of BOTH gate and up: stages x once, Wg & Wu tiles per k-iter
// (32 MFMA per 2 barriers), LoRA expert loop shared, SwiGLU in registers,
// writes h only (no g round-trip).
__global__ __launch_bounds__(256) void gemm_gateup_kernel(
    const unsigned short* __restrict__ xb, const unsigned short* __restrict__ wgt,
    const unsigned short* __restrict__ wut, const unsigned short* __restrict__ Tm,
    const unsigned short* __restrict__ btg, const unsigned short* __restrict__ btu,
    const int* __restrict__ idx, unsigned short* __restrict__ hbuf) {
  __shared__ __align__(16) unsigned short sA[4096], sBg[4096], sBu[4096], sTu[4096];
  __shared__ int es_s[128];
  floatx4 accg[16], accu[16];
#pragma unroll
  for (int i = 0; i < 16; i++)
#pragma unroll
    for (int j = 0; j < 4; j++) { accg[i][j] = 0.f; accu[i][j] = 0.f; }
  const int row0 = blockIdx.y * 128, col0 = blockIdx.x * 128;
  const int tid = threadIdx.x;
  const int wave = tid >> 6, lane = tid & 63;
  const int wr = wave >> 1, wc = wave & 1;
  const int q = lane >> 4, m16 = lane & 15;

  // ---- main K loop over D ----
  for (int k0 = 0; k0 < DDIM; k0 += 32) {
    __syncthreads();
#pragma unroll
    for (int rr = 0; rr < 2; rr++) {
      int e = tid * 8 + rr * 2048;
      int r = e >> 5, kk = e & 31;
      gload_lds16(xb  + (size_t)(row0 + r) * DDIM + (k0 + kk), sA + e);
      gload_lds16(wgt + (size_t)(col0 + r) * DDIM + (k0 + kk), sBg + e);
      gload_lds16(wut + (size_t)(col0 + r) * DDIM + (k0 + kk), sBu + e);
    }
    __syncthreads();
    short8 a[4], bg[4], bu[4];
#pragma unroll
    for (int m = 0; m < 4; m++)
      a[m] = *(const short8*)(sA + (wr * 64 + m * 16 + m16) * 32 + q * 8);
#pragma unroll
    for (int n = 0; n < 4; n++) {
      bg[n] = *(const short8*)(sBg + (wc * 64 + n * 16 + m16) * 32 + q * 8);
      bu[n] = *(const short8*)(sBu + (wc * 64 + n * 16 + m16) * 32 + q * 8);
    }
#pragma unroll
    for (int m = 0; m < 4; m++)
#pragma unroll
      for (int n = 0; n < 4; n++) {
        accg[m * 4 + n] = __builtin_amdgcn_mfma_f32_16x16x32_bf16(a[m], bg[n], accg[m * 4 + n], 0, 0, 0);
        accu[m * 4 + n] = __builtin_amdgcn_mfma_f32_16x16x32_bf16(a[m], bu[n], accu[m * 4 + n], 0, 0, 0);
      }
  }

  // ---- LoRA epilogue: acc += mask_e(T_sel) @ B_e for gate and up ----
  __syncthreads();
  if (tid < 128) es_s[tid] = idx[row0 + tid];
#pragma unroll
  for (int rr = 0; rr < 2; rr++) {
    int e = tid * 8 + rr * 2048;
    int r = e >> 5, kk = e & 31;
    int ex = idx[row0 + r];
    const unsigned short* base = Tm + (size_t)(row0 + r) * 512 + ex * 32 + kk;
    *(floatx4*)(sA + e)  = *(const floatx4*)(base);        // gate half
    *(floatx4*)(sTu + e) = *(const floatx4*)(base + 256);  // up half
  }
  __syncthreads();
  short8 tag[4], tau[4]; int erow[4];
#pragma unroll
  for (int m = 0; m < 4; m++) {
    int rloc = wr * 64 + m * 16 + m16;
    tag[m] = *(const short8*)(sA  + rloc * 32 + q * 8);
    tau[m] = *(const short8*)(sTu + rloc * 32 + q * 8);
    erow[m] = es_s[rloc];
  }
  short8 zero;
#pragma unroll
  for (int i = 0; i < 8; i++) zero[i] = 0;
  for (int ee = 0; ee < NEXP; ee++) {
    __syncthreads();
#pragma unroll
    for (int rr = 0; rr < 2; rr++) {
      int e2 = tid * 8 + rr * 2048;
      int c = e2 >> 5, kk = e2 & 31;
      *(floatx4*)(sBg + e2) = *(const floatx4*)(btg + ((size_t)ee * IDIM + col0 + c) * RLORA + kk);
      *(floatx4*)(sBu + e2) = *(const floatx4*)(btu + ((size_t)ee * IDIM + col0 + c) * RLORA + kk);
    }
    __syncthreads();
    short8 bg[4], bu[4];
#pragma unroll
    for (int n = 0; n < 4; n++) {
      bg[n] = *(const short8*)(sBg + (wc * 64 + n * 16 + m16) * 32 + q * 8);
      bu[n] = *(const short8*)(sBu + (wc * 64 + n * 16 + m16) * 32 + q * 8);
    }
#pragma unroll
    for (int m = 0; m < 4; m++) {
      short8 ag = (erow[m] == ee) ? tag[m] : zero;
      short8 au = (erow[m] == ee) ? tau[m] : zero;
#pragma unroll
      for (int n = 0; n < 4; n++) {
        accg[m * 4 + n] = __builtin_amdgcn_mfma_f32_16x16x32_bf16(ag, bg[n], accg[m * 4 + n], 0, 0, 0);
        accu[m * 4 + n] = __builtin_amdgcn_mfma_f32_16x16x32_bf16(au, bu[n], accu[m * 4 + n], 0, 0, 0);
      }
    }
  }

  // ---- SwiGLU in registers, write h only ----
#pragma unroll
  for (int m = 0; m < 4; m++)
#pragma unroll
    for (int n = 0; n < 4; n++)
#pragma unroll
      for (int r = 0; r < 4; r++) {
        int grow = row0 + wr * 64 + m * 16 + q * 4 + r;
        int gcol = col0 + wc * 64 + n * 16 + m16;
        float gv = accg[m * 4 + n][r];
        float hv = gv / (1.f + __expf(-gv)) * accu[m * 4 + n][r];
        hbuf[(size_t)grow * IDIM + gcol] = f2bf(hv);
      }
}

// ---------------- down GEMM ----------------
__global__ __launch_bounds__(256) void gemm_down_kernel(
    const unsigned short* __restrict__ hb, const unsigned short* __restrict__ wdt,
    float* __restrict__ out) {
  __shared__ __align__(16) unsigned short sA[4096], sB[4096];
  floatx4 acc[16];
#pragma unroll
  for (int i = 0; i < 16; i++)
#pragma unroll
    for (int j = 0; j < 4; j++) acc[i][j] = 0.f;
  int row0 = blockIdx.y * 128, col0 = blockIdx.x * 128;
  mm_main(hb, wdt, IDIM, row0, col0, sA, sB, acc);
  const int wave = threadIdx.x >> 6, lane = threadIdx.x & 63;
  const int wr = wave >> 1, wc = wave & 1;
  const int q = lane >> 4, m16 = lane & 15;
#pragma unroll
  for (int m = 0; m < 4; m++)
#pragma unroll
    for (int n = 0; n < 4; n++)
#pragma unroll
      for (int r = 0; r < 4; r++) {
        int grow = row0 + wr * 64 + m * 16 + q * 4 + r;
        int gcol = col0 + wc * 64 + n * 16 + m16;
        out[(size_t)grow * DDIM + gcol] = acc[m * 4 + n][r];
      }
}

extern "C" void kernel_launch(void* const* d_in, const int* in_sizes, int n_in,
                              void* d_out, int out_size, void* d_ws, size_t ws_size,
                              hipStream_t stream) {
  const float* x  = (const float*)d_in[0];
  const float* rw = (const float*)d_in[1];
  const float* Ag = (const float*)d_in[2];
  const float* Bg = (const float*)d_in[3];
  const float* Au = (const float*)d_in[4];
  const float* Bu = (const float*)d_in[5];
  const float* Wg = (const float*)d_in[6];
  const float* Wu = (const float*)d_in[7];
  const float* Wd = (const float*)d_in[8];
  float* out = (float*)d_out;
  float* logits = out + (size_t)N_TOK * DDIM;

  char* ws = (char*)d_ws;
  size_t off = 0;
  auto alloc = [&](size_t bytes) {
    char* p = ws + off;
    off += (bytes + 255) & ~(size_t)255;
    return p;
  };
  unsigned short* xb  = (unsigned short*)alloc((size_t)N_TOK * DDIM * 2);
  unsigned short* wgt = (unsigned short*)alloc((size_t)IDIM * DDIM * 2);
  unsigned short* wut = (unsigned short*)alloc((size_t)IDIM * DDIM * 2);
  unsigned short* wdt = (unsigned short*)alloc((size_t)DDIM * IDIM * 2);
  unsigned short* aat = (unsigned short*)alloc((size_t)512 * DDIM * 2);
  unsigned short* btg = (unsigned short*)alloc((size_t)NEXP * IDIM * RLORA * 2);
  unsigned short* btu = (unsigned short*)alloc((size_t)NEXP * IDIM * RLORA * 2);
  unsigned short* Tm  = (unsigned short*)alloc((size_t)N_TOK * 512 * 2);
  unsigned short* hbuf= (unsigned short*)alloc((size_t)N_TOK * IDIM * 2);
  int* idx = (int*)alloc((size_t)N_TOK * 4);

  router_kernel<<<N_TOK / 4, 256, 0, stream>>>(x, rw, xb, logits, idx);
  transpose_w_kernel<<<dim3(IDIM / 32, DDIM / 32), 256, 0, stream>>>(Wg, wgt, DDIM, IDIM);
  transpose_w_kernel<<<dim3(IDIM / 32, DDIM / 32), 256, 0, stream>>>(Wu, wut, DDIM, IDIM);
  transpose_w_kernel<<<dim3(DDIM / 32, IDIM / 32), 256, 0, stream>>>(Wd, wdt, IDIM, DDIM);
  pack_a_kernel<<<4096, 256, 0, stream>>>(Ag, Au, aat);
  transpose_b_kernel<<<dim3(IDIM / 32, NEXP, 2), 256, 0, stream>>>(Bg, Bu, btg, btu);
  gemm_t_kernel<<<dim3(4, N_TOK / 128), 256, 0, stream>>>(xb, aat, Tm);
  gemm_gateup_kernel<<<dim3(IDIM / 128, N_TOK / 128), 256, 0, stream>>>(
      xb, wgt, wut, Tm, btg, btu, idx, hbuf);
  gemm_down_kernel<<<dim3(DDIM / 128, N_TOK / 128), 256, 0, stream>>>(hbuf, wdt, out);
}

// Round 3
// 1238.012 us; speedup vs baseline: 1.2032x; 1.2032x over previous
//
#include <hip/hip_runtime.h>
#include <stdint.h>

#define N_TOK 8192
#define DDIM 2048
#define IDIM 6144
#define NEXP 8
#define RLORA 32
#define NCHUNK 64
#define CHUNK 128

typedef __attribute__((ext_vector_type(8))) short short8;
typedef __attribute__((ext_vector_type(4))) float floatx4;
typedef __attribute__((ext_vector_type(4))) unsigned short ushortx4;

__device__ __forceinline__ unsigned short f2bf(float f) {
  union { float f; unsigned u; } v; v.f = f;
  unsigned u = v.u;
  unsigned r = (u + 0x7fffu + ((u >> 16) & 1u)) >> 16;
  return (unsigned short)r;
}
__device__ __forceinline__ float bf2f(unsigned short s) {
  union { unsigned u; float f; } v; v.u = ((unsigned)s) << 16;
  return v.f;
}

__device__ __forceinline__ void gload_lds16(const void* g, void* l) {
  __builtin_amdgcn_global_load_lds(
      (const __attribute__((address_space(1))) void*)g,
      (__attribute__((address_space(3))) void*)l, 16, 0, 0);
}

// ---------------- router: logits (fp32, original order) + top-1 idx ----------------
__global__ __launch_bounds__(256) void router_kernel(
    const float* __restrict__ x, const float* __restrict__ rw,
    float* __restrict__ logits_out, int* __restrict__ idx) {
  int wave = threadIdx.x >> 6, lane = threadIdx.x & 63;
  int n = blockIdx.x * 4 + wave;
  const float* xr = x + (size_t)n * DDIM;
  float acc[NEXP];
#pragma unroll
  for (int e = 0; e < NEXP; e++) acc[e] = 0.f;
#pragma unroll
  for (int j = 0; j < 8; j++) {
    int d = j * 256 + lane * 4;
    floatx4 v = *(const floatx4*)(xr + d);
    const float* rwd = rw + (size_t)d * NEXP;
#pragma unroll
    for (int t = 0; t < 4; t++) {
      float xv = v[t];
      const float* rr = rwd + t * NEXP;
#pragma unroll
      for (int e = 0; e < NEXP; e++) acc[e] += xv * rr[e];
    }
  }
#pragma unroll
  for (int off = 32; off > 0; off >>= 1) {
#pragma unroll
    for (int e = 0; e < NEXP; e++) acc[e] += __shfl_xor(acc[e], off, 64);
  }
  if (lane == 0) {
    float best = acc[0]; int bi = 0;
#pragma unroll
    for (int e = 1; e < NEXP; e++)
      if (acc[e] > best) { best = acc[e]; bi = e; }
    idx[n] = bi;
#pragma unroll
    for (int e = 0; e < NEXP; e++) logits_out[(size_t)n * NEXP + e] = acc[e];
  }
}

// ---------------- sort step 1: per-chunk expert counts ----------------
__global__ __launch_bounds__(128) void count_kernel(
    const int* __restrict__ idx, int* __restrict__ cnt) {
  __shared__ int h[NEXP];
  if (threadIdx.x < NEXP) h[threadIdx.x] = 0;
  __syncthreads();
  int n = blockIdx.x * CHUNK + threadIdx.x;
  atomicAdd(&h[idx[n]], 1);
  __syncthreads();
  if (threadIdx.x < NEXP) cnt[blockIdx.x * NEXP + threadIdx.x] = h[threadIdx.x];
}

// ---------------- sort step 2: exclusive scan (expert-major) ----------------
__global__ __launch_bounds__(64) void scan_kernel(
    const int* __restrict__ cnt, int* __restrict__ off) {
  __shared__ int tot[NEXP], base[NEXP];
  int t = threadIdx.x;
  if (t < NEXP) {
    int s = 0;
    for (int c = 0; c < NCHUNK; c++) s += cnt[c * NEXP + t];
    tot[t] = s;
  }
  __syncthreads();
  if (t == 0) {
    int run = 0;
    for (int e = 0; e < NEXP; e++) { base[e] = run; run += tot[e]; }
  }
  __syncthreads();
  if (t < NEXP) {
    int run = base[t];
    for (int c = 0; c < NCHUNK; c++) { off[c * NEXP + t] = run; run += cnt[c * NEXP + t]; }
  }
}

// ---------------- sort step 3: ranks -> permutation ----------------
__global__ __launch_bounds__(64) void rank_kernel(
    const int* __restrict__ idx, const int* __restrict__ off,
    int* __restrict__ sortpos, int* __restrict__ orig, int* __restrict__ eidx) {
  if (threadIdx.x != 0) return;
  int c = blockIdx.x;
  int lc[NEXP];
#pragma unroll
  for (int e = 0; e < NEXP; e++) lc[e] = 0;
  for (int t = 0; t < CHUNK; t++) {
    int n = c * CHUNK + t;
    int e = idx[n];
    int dst = off[c * NEXP + e] + lc[e]++;
    sortpos[n] = dst;
    orig[dst] = n;
    eidx[dst] = e;
  }
}

// ---------------- permuted x -> bf16 (row-coalesced) ----------------
__global__ __launch_bounds__(256) void permute_x_kernel(
    const float* __restrict__ x, const int* __restrict__ sortpos,
    unsigned short* __restrict__ xb) {
  int wave = threadIdx.x >> 6, lane = threadIdx.x & 63;
  int n = blockIdx.x * 4 + wave;
  int dst = sortpos[n];
  const float* xr = x + (size_t)n * DDIM;
  unsigned short* xbr = xb + (size_t)dst * DDIM;
#pragma unroll
  for (int j = 0; j < 8; j++) {
    int d = j * 256 + lane * 4;
    floatx4 v = *(const floatx4*)(xr + d);
    ushortx4 s;
    s[0] = f2bf(v[0]); s[1] = f2bf(v[1]); s[2] = f2bf(v[2]); s[3] = f2bf(v[3]);
    *(ushortx4*)(xbr + d) = s;
  }
}

// ---------------- fp32 [Rr][Cc] -> bf16 [Cc][Rr] transpose ----------------
__global__ __launch_bounds__(256) void transpose_w_kernel(
    const float* __restrict__ in, unsigned short* __restrict__ out, int Rr, int Cc) {
  __shared__ float lds[32][33];
  int r0 = blockIdx.y * 32, c0 = blockIdx.x * 32;
  int tx = threadIdx.x & 31, ty = threadIdx.x >> 5;
#pragma unroll
  for (int k = 0; k < 4; k++) {
    int r = ty + k * 8;
    lds[r][tx] = in[(size_t)(r0 + r) * Cc + c0 + tx];
  }
  __syncthreads();
#pragma unroll
  for (int k = 0; k < 4; k++) {
    int cc = ty + k * 8;
    out[(size_t)(c0 + cc) * Rr + r0 + tx] = f2bf(lds[tx][cc]);
  }
}

// ---------------- pack A_gate/A_up -> aat[512][2048] bf16 (row = h*256+e*32+r) ----------------
__global__ __launch_bounds__(256) void pack_a_kernel(
    const float* __restrict__ Ag, const float* __restrict__ Au,
    unsigned short* __restrict__ aat) {
  int o = blockIdx.x * 256 + threadIdx.x;    // [0, 2^20)
  int h = o >> 19;
  int oo = o & ((1 << 19) - 1);
  int c = oo >> 11, d = oo & 2047;           // c in [0,256)
  int e = c >> 5, r = c & 31;
  const float* src = h ? Au : Ag;
  float v = src[(e << 16) + (d << 5) + r];   // A[e][d][r]
  aat[(size_t)(h * 256 + c) * DDIM + d] = f2bf(v);
}

// ---------------- B[e][R][I] fp32 -> Bt[e][I][R] bf16 ----------------
__global__ __launch_bounds__(256) void transpose_b_kernel(
    const float* __restrict__ Bg, const float* __restrict__ Bu,
    unsigned short* __restrict__ btg, unsigned short* __restrict__ btu) {
  __shared__ float lds[32][33];
  int i0 = blockIdx.x * 32, e = blockIdx.y;
  const float* in = blockIdx.z ? Bu : Bg;
  unsigned short* out = blockIdx.z ? btu : btg;
  int tx = threadIdx.x & 31, ty = threadIdx.x >> 5;
#pragma unroll
  for (int k = 0; k < 4; k++) {
    int r = ty + k * 8;
    lds[r][tx] = in[((size_t)e * RLORA + r) * IDIM + i0 + tx];
  }
  __syncthreads();
#pragma unroll
  for (int k = 0; k < 4; k++) {
    int ii = ty + k * 8;
    out[((size_t)e * IDIM + i0 + ii) * RLORA + tx] = f2bf(lds[tx][ii]);
  }
}

// ---------------- Tsel[8192][64]: per-token own-expert x@[A_gate|A_up] ----------------
// Rows sorted by expert: per 128-row tile loop experts present (usually 1).
__global__ __launch_bounds__(256) void gemm_tsel_kernel(
    const unsigned short* __restrict__ xb, const unsigned short* __restrict__ aat,
    const int* __restrict__ eidx, unsigned short* __restrict__ Tsel) {
  __shared__ __align__(16) unsigned short sA[4096], sB[2048];
  __shared__ int es_s[128];
  const int row0 = blockIdx.x * 128;
  const int tid = threadIdx.x;
  const int wave = tid >> 6, lane = tid & 63;
  const int wr = wave >> 1, wc = wave & 1;
  const int q = lane >> 4, m16 = lane & 15;
  if (tid < 128) es_s[tid] = eidx[row0 + tid];
  __syncthreads();
  const int emin = es_s[0], emax = es_s[127];
  int erow[4];
#pragma unroll
  for (int m = 0; m < 4; m++) erow[m] = es_s[wr * 64 + m * 16 + m16];
  floatx4 acc[8];
#pragma unroll
  for (int i = 0; i < 8; i++)
#pragma unroll
    for (int j = 0; j < 4; j++) acc[i][j] = 0.f;
  short8 zero;
#pragma unroll
  for (int i = 0; i < 8; i++) zero[i] = 0;
  for (int ee = emin; ee <= emax; ee++) {
    for (int k0 = 0; k0 < DDIM; k0 += 32) {
      __syncthreads();
#pragma unroll
      for (int rr = 0; rr < 2; rr++) {
        int e = tid * 8 + rr * 2048;
        int r = e >> 5, kk = e & 31;
        gload_lds16(xb + (size_t)(row0 + r) * DDIM + (k0 + kk), sA + e);
      }
      {
        int e2 = tid * 8;
        int c = e2 >> 5, kk = e2 & 31;
        int srow = (c < 32) ? (ee * 32 + c) : (256 + ee * 32 + (c - 32));
        gload_lds16(aat + (size_t)srow * DDIM + (k0 + kk), sB + e2);
      }
      __syncthreads();
      short8 a[4], b[2];
#pragma unroll
      for (int m = 0; m < 4; m++) {
        short8 av = *(const short8*)(sA + (wr * 64 + m * 16 + m16) * 32 + q * 8);
        a[m] = (erow[m] == ee) ? av : zero;
      }
#pragma unroll
      for (int n = 0; n < 2; n++)
        b[n] = *(const short8*)(sB + (wc * 32 + n * 16 + m16) * 32 + q * 8);
#pragma unroll
      for (int m = 0; m < 4; m++)
#pragma unroll
        for (int n = 0; n < 2; n++)
          acc[m * 2 + n] = __builtin_amdgcn_mfma_f32_16x16x32_bf16(a[m], b[n], acc[m * 2 + n], 0, 0, 0);
    }
  }
#pragma unroll
  for (int m = 0; m < 4; m++)
#pragma unroll
    for (int n = 0; n < 2; n++)
#pragma unroll
      for (int r = 0; r < 4; r++) {
        int grow = row0 + wr * 64 + m * 16 + q * 4 + r;
        int gcol = wc * 32 + n * 16 + m16;
        Tsel[(size_t)grow * 64 + gcol] = f2bf(acc[m * 2 + n][r]);
      }
}

// ---------------- shared GEMM main loop ----------------
__device__ __forceinline__ void mm_main(const unsigned short* __restrict__ Ab,
                                        const unsigned short* __restrict__ Bb,
                                        int K, int row0, int col0,
                                        unsigned short* sA, unsigned short* sB,
                                        floatx4* acc) {
  const int tid = threadIdx.x;
  const int wave = tid >> 6, lane = tid & 63;
  const int wr = wave >> 1, wc = wave & 1;
  const int q = lane >> 4, m16 = lane & 15;
  for (int k0 = 0; k0 < K; k0 += 32) {
    __syncthreads();
#pragma unroll
    for (int rr = 0; rr < 2; rr++) {
      int e = tid * 8 + rr * 2048;
      int r = e >> 5, kk = e & 31;
      gload_lds16(Ab + (size_t)(row0 + r) * K + (k0 + kk), sA + e);
      gload_lds16(Bb + (size_t)(col0 + r) * K + (k0 + kk), sB + e);
    }
    __syncthreads();
    short8 a[4], b[4];
#pragma unroll
    for (int m = 0; m < 4; m++)
      a[m] = *(const short8*)(sA + (wr * 64 + m * 16 + m16) * 32 + q * 8);
#pragma unroll
    for (int n = 0; n < 4; n++)
      b[n] = *(const short8*)(sB + (wc * 64 + n * 16 + m16) * 32 + q * 8);
#pragma unroll
    for (int m = 0; m < 4; m++)
#pragma unroll
      for (int n = 0; n < 4; n++)
        acc[m * 4 + n] = __builtin_amdgcn_mfma_f32_16x16x32_bf16(a[m], b[n], acc[m * 4 + n], 0, 0, 0);
  }
}

// ---------------- LoRA epilogue over experts present in this (sorted) row tile ----------------
__device__ __forceinline__ void lora_epilogue(const unsigned short* __restrict__ Tsel,
                                              const unsigned short* __restrict__ Bt,
                                              const int* __restrict__ eidx,
                                              int half, int row0, int col0,
                                              unsigned short* sA, unsigned short* sB,
                                              int* es_s, floatx4* acc) {
  const int tid = threadIdx.x;
  const int wave = tid >> 6, lane = tid & 63;
  const int wr = wave >> 1, wc = wave & 1;
  const int q = lane >> 4, m16 = lane & 15;
  __syncthreads();
  if (tid < 128) es_s[tid] = eidx[row0 + tid];
#pragma unroll
  for (int rr = 0; rr < 2; rr++) {
    int e = tid * 8 + rr * 2048;
    int r = e >> 5, kk = e & 31;
    *(floatx4*)(sA + e) = *(const floatx4*)(Tsel + (size_t)(row0 + r) * 64 + half * 32 + kk);
  }
  __syncthreads();
  const int emin = es_s[0], emax = es_s[127];
  short8 ta[4]; int erow[4];
#pragma unroll
  for (int m = 0; m < 4; m++) {
    int rloc = wr * 64 + m * 16 + m16;
    ta[m] = *(const short8*)(sA + rloc * 32 + q * 8);
    erow[m] = es_s[rloc];
  }
  short8 zero;
#pragma unroll
  for (int i = 0; i < 8; i++) zero[i] = 0;
  for (int ee = emin; ee <= emax; ee++) {
    __syncthreads();
#pragma unroll
    for (int rr = 0; rr < 2; rr++) {
      int e2 = tid * 8 + rr * 2048;
      int c = e2 >> 5, kk = e2 & 31;
      *(floatx4*)(sB + e2) = *(const floatx4*)(Bt + ((size_t)ee * IDIM + col0 + c) * RLORA + kk);
    }
    __syncthreads();
    short8 bfr[4];
#pragma unroll
    for (int n = 0; n < 4; n++)
      bfr[n] = *(const short8*)(sB + (wc * 64 + n * 16 + m16) * 32 + q * 8);
#pragma unroll
    for (int m = 0; m < 4; m++) {
      short8 am = (erow[m] == ee) ? ta[m] : zero;
#pragma unroll
      for (int n = 0; n < 4; n++)
        acc[m * 4 + n] = __builtin_amdgcn_mfma_f32_16x16x32_bf16(am, bfr[n], acc[m * 4 + n], 0, 0, 0);
    }
  }
}

// XCD-aware swizzle: lin%8 ~ XCD; give each XCD a contiguous column band so its
// 4MB L2 holds the whole weight band (6 col-tiles * 128 * 2048 * 2B = 3MB).
__device__ __forceinline__ void swizzle_gu(int lin, int& bx, int& by) {
  int xcd = lin & 7, slot = lin >> 3;      // slot in [0,384)
  bx = xcd * 6 + slot % 6;                 // col tile [0,48)
  by = slot / 6;                           // row tile [0,64)
}

__global__ __launch_bounds__(256) void gemm_gate_kernel(
    const unsigned short* __restrict__ xb, const unsigned short* __restrict__ wgt,
    const unsigned short* __restrict__ Tsel, const unsigned short* __restrict__ btg,
    const int* __restrict__ eidx, unsigned short* __restrict__ gbuf) {
  __shared__ __align__(16) unsigned short sA[4096], sB[4096];
  __shared__ int es_s[128];
  floatx4 acc[16];
#pragma unroll
  for (int i = 0; i < 16; i++)
#pragma unroll
    for (int j = 0; j < 4; j++) acc[i][j] = 0.f;
  int bx, by; swizzle_gu(blockIdx.x, bx, by);
  int row0 = by * 128, col0 = bx * 128;
  mm_main(xb, wgt, DDIM, row0, col0, sA, sB, acc);
  lora_epilogue(Tsel, btg, eidx, 0, row0, col0, sA, sB, es_s, acc);
  const int wave = threadIdx.x >> 6, lane = threadIdx.x & 63;
  const int wr = wave >> 1, wc = wave & 1;
  const int q = lane >> 4, m16 = lane & 15;
#pragma unroll
  for (int m = 0; m < 4; m++)
#pragma unroll
    for (int n = 0; n < 4; n++)
#pragma unroll
      for (int r = 0; r < 4; r++) {
        int grow = row0 + wr * 64 + m * 16 + q * 4 + r;
        int gcol = col0 + wc * 64 + n * 16 + m16;
        gbuf[(size_t)grow * IDIM + gcol] = f2bf(acc[m * 4 + n][r]);
      }
}

__global__ __launch_bounds__(256) void gemm_up_kernel(
    const unsigned short* __restrict__ xb, const unsigned short* __restrict__ wut,
    const unsigned short* __restrict__ Tsel, const unsigned short* __restrict__ btu,
    const int* __restrict__ eidx, unsigned short* __restrict__ gbuf) {
  __shared__ __align__(16) unsigned short sA[4096], sB[4096];
  __shared__ int es_s[128];
  floatx4 acc[16];
#pragma unroll
  for (int i = 0; i < 16; i++)
#pragma unroll
    for (int j = 0; j < 4; j++) acc[i][j] = 0.f;
  int bx, by; swizzle_gu(blockIdx.x, bx, by);
  int row0 = by * 128, col0 = bx * 128;
  mm_main(xb, wut, DDIM, row0, col0, sA, sB, acc);
  lora_epilogue(Tsel, btu, eidx, 1, row0, col0, sA, sB, es_s, acc);
  const int wave = threadIdx.x >> 6, lane = threadIdx.x & 63;
  const int wr = wave >> 1, wc = wave & 1;
  const int q = lane >> 4, m16 = lane & 15;
#pragma unroll
  for (int m = 0; m < 4; m++)
#pragma unroll
    for (int n = 0; n < 4; n++)
#pragma unroll
      for (int r = 0; r < 4; r++) {
        int grow = row0 + wr * 64 + m * 16 + q * 4 + r;
        int gcol = col0 + wc * 64 + n * 16 + m16;
        size_t o = (size_t)grow * IDIM + gcol;
        float gv = bf2f(gbuf[o]);
        float hv = gv / (1.f + __expf(-gv)) * acc[m * 4 + n][r];
        gbuf[o] = f2bf(hv);   // h overwrites g in place
      }
}

__global__ __launch_bounds__(256) void gemm_down_kernel(
    const unsigned short* __restrict__ hb, const unsigned short* __restrict__ wdt,
    const int* __restrict__ orig, float* __restrict__ out) {
  __shared__ __align__(16) unsigned short sA[4096], sB[4096];
  floatx4 acc[16];
#pragma unroll
  for (int i = 0; i < 16; i++)
#pragma unroll
    for (int j = 0; j < 4; j++) acc[i][j] = 0.f;
  int lin = blockIdx.x;
  int xcd = lin & 7, slot = lin >> 3;      // slot in [0,128)
  int bx = xcd * 2 + (slot & 1);           // col tile [0,16)
  int by = slot >> 1;                      // row tile [0,64)
  int row0 = by * 128, col0 = bx * 128;
  mm_main(hb, wdt, IDIM, row0, col0, sA, sB, acc);
  const int wave = threadIdx.x >> 6, lane = threadIdx.x & 63;
  const int wr = wave >> 1, wc = wave & 1;
  const int q = lane >> 4, m16 = lane & 15;
#pragma unroll
  for (int m = 0; m < 4; m++)
#pragma unroll
    for (int n = 0; n < 4; n++)
#pragma unroll
      for (int r = 0; r < 4; r++) {
        int grow = row0 + wr * 64 + m * 16 + q * 4 + r;
        int orow = orig[grow];
        int gcol = col0 + wc * 64 + n * 16 + m16;
        out[(size_t)orow * DDIM + gcol] = acc[m * 4 + n][r];
      }
}

extern "C" void kernel_launch(void* const* d_in, const int* in_sizes, int n_in,
                              void* d_out, int out_size, void* d_ws, size_t ws_size,
                              hipStream_t stream) {
  const float* x  = (const float*)d_in[0];
  const float* rw = (const float*)d_in[1];
  const float* Ag = (const float*)d_in[2];
  const float* Bg = (const float*)d_in[3];
  const float* Au = (const float*)d_in[4];
  const float* Bu = (const float*)d_in[5];
  const float* Wg = (const float*)d_in[6];
  const float* Wu = (const float*)d_in[7];
  const float* Wd = (const float*)d_in[8];
  float* out = (float*)d_out;
  float* logits = out + (size_t)N_TOK * DDIM;

  char* ws = (char*)d_ws;
  size_t off = 0;
  auto alloc = [&](size_t bytes) {
    char* p = ws + off;
    off += (bytes + 255) & ~(size_t)255;
    return p;
  };
  unsigned short* xb  = (unsigned short*)alloc((size_t)N_TOK * DDIM * 2);
  unsigned short* wgt = (unsigned short*)alloc((size_t)IDIM * DDIM * 2);
  unsigned short* wut = (unsigned short*)alloc((size_t)IDIM * DDIM * 2);
  unsigned short* wdt = (unsigned short*)alloc((size_t)DDIM * IDIM * 2);
  unsigned short* aat = (unsigned short*)alloc((size_t)512 * DDIM * 2);
  unsigned short* btg = (unsigned short*)alloc((size_t)NEXP * IDIM * RLORA * 2);
  unsigned short* btu = (unsigned short*)alloc((size_t)NEXP * IDIM * RLORA * 2);
  unsigned short* Tsel= (unsigned short*)alloc((size_t)N_TOK * 64 * 2);
  unsigned short* gbuf= (unsigned short*)alloc((size_t)N_TOK * IDIM * 2);
  int* idx     = (int*)alloc((size_t)N_TOK * 4);
  int* sortpos = (int*)alloc((size_t)N_TOK * 4);
  int* orig    = (int*)alloc((size_t)N_TOK * 4);
  int* eidx    = (int*)alloc((size_t)N_TOK * 4);
  int* cnt     = (int*)alloc((size_t)NCHUNK * NEXP * 4);
  int* offb    = (int*)alloc((size_t)NCHUNK * NEXP * 4);

  router_kernel<<<N_TOK / 4, 256, 0, stream>>>(x, rw, logits, idx);
  count_kernel<<<NCHUNK, 128, 0, stream>>>(idx, cnt);
  scan_kernel<<<1, 64, 0, stream>>>(cnt, offb);
  rank_kernel<<<NCHUNK, 64, 0, stream>>>(idx, offb, sortpos, orig, eidx);
  permute_x_kernel<<<N_TOK / 4, 256, 0, stream>>>(x, sortpos, xb);
  transpose_w_kernel<<<dim3(IDIM / 32, DDIM / 32), 256, 0, stream>>>(Wg, wgt, DDIM, IDIM);
  transpose_w_kernel<<<dim3(IDIM / 32, DDIM / 32), 256, 0, stream>>>(Wu, wut, DDIM, IDIM);
  transpose_w_kernel<<<dim3(DDIM / 32, IDIM / 32), 256, 0, stream>>>(Wd, wdt, IDIM, DDIM);
  pack_a_kernel<<<4096, 256, 0, stream>>>(Ag, Au, aat);
  transpose_b_kernel<<<dim3(IDIM / 32, NEXP, 2), 256, 0, stream>>>(Bg, Bu, btg, btu);
  gemm_tsel_kernel<<<N_TOK / 128, 256, 0, stream>>>(xb, aat, eidx, Tsel);
  gemm_gate_kernel<<<(IDIM / 128) * (N_TOK / 128), 256, 0, stream>>>(xb, wgt, Tsel, btg, eidx, gbuf);
  gemm_up_kernel<<<(IDIM / 128) * (N_TOK / 128), 256, 0, stream>>>(xb, wut, Tsel, btu, eidx, gbuf);
  gemm_down_kernel<<<(DDIM / 128) * (N_TOK / 128), 256, 0, stream>>>(gbuf, wdt, orig, out);
}

// Round 4
// 1215.082 us; speedup vs baseline: 1.2259x; 1.0189x over previous
//
#include <hip/hip_runtime.h>
#include <stdint.h>

#define N_TOK 8192
#define DDIM 2048
#define IDIM 6144
#define NEXP 8
#define RLORA 32
#define NCHUNK 64
#define CHUNK 128

typedef __attribute__((ext_vector_type(8))) short short8;
typedef __attribute__((ext_vector_type(4))) float floatx4;
typedef __attribute__((ext_vector_type(4))) unsigned short ushortx4;

__device__ __forceinline__ unsigned short f2bf(float f) {
  union { float f; unsigned u; } v; v.f = f;
  unsigned u = v.u;
  unsigned r = (u + 0x7fffu + ((u >> 16) & 1u)) >> 16;
  return (unsigned short)r;
}

__device__ __forceinline__ void gload_lds16(const void* g, void* l) {
  __builtin_amdgcn_global_load_lds(
      (const __attribute__((address_space(1))) void*)g,
      (__attribute__((address_space(3))) void*)l, 16, 0, 0);
}

// ---------------- router: logits (fp32, original order) + top-1 idx ----------------
__global__ __launch_bounds__(256) void router_kernel(
    const float* __restrict__ x, const float* __restrict__ rw,
    float* __restrict__ logits_out, int* __restrict__ idx) {
  int wave = threadIdx.x >> 6, lane = threadIdx.x & 63;
  int n = blockIdx.x * 4 + wave;
  const float* xr = x + (size_t)n * DDIM;
  float acc[NEXP];
#pragma unroll
  for (int e = 0; e < NEXP; e++) acc[e] = 0.f;
#pragma unroll
  for (int j = 0; j < 8; j++) {
    int d = j * 256 + lane * 4;
    floatx4 v = *(const floatx4*)(xr + d);
    const float* rwd = rw + (size_t)d * NEXP;
#pragma unroll
    for (int t = 0; t < 4; t++) {
      float xv = v[t];
      const float* rr = rwd + t * NEXP;
#pragma unroll
      for (int e = 0; e < NEXP; e++) acc[e] += xv * rr[e];
    }
  }
#pragma unroll
  for (int off = 32; off > 0; off >>= 1) {
#pragma unroll
    for (int e = 0; e < NEXP; e++) acc[e] += __shfl_xor(acc[e], off, 64);
  }
  if (lane == 0) {
    float best = acc[0]; int bi = 0;
#pragma unroll
    for (int e = 1; e < NEXP; e++)
      if (acc[e] > best) { best = acc[e]; bi = e; }
    idx[n] = bi;
#pragma unroll
    for (int e = 0; e < NEXP; e++) logits_out[(size_t)n * NEXP + e] = acc[e];
  }
}

// ---------------- sort step 1: per-chunk expert counts ----------------
__global__ __launch_bounds__(128) void count_kernel(
    const int* __restrict__ idx, int* __restrict__ cnt) {
  __shared__ int h[NEXP];
  if (threadIdx.x < NEXP) h[threadIdx.x] = 0;
  __syncthreads();
  int n = blockIdx.x * CHUNK + threadIdx.x;
  atomicAdd(&h[idx[n]], 1);
  __syncthreads();
  if (threadIdx.x < NEXP) cnt[blockIdx.x * NEXP + threadIdx.x] = h[threadIdx.x];
}

// ---------------- sort step 2: exclusive scan (expert-major) ----------------
__global__ __launch_bounds__(64) void scan_kernel(
    const int* __restrict__ cnt, int* __restrict__ off) {
  __shared__ int tot[NEXP], base[NEXP];
  int t = threadIdx.x;
  if (t < NEXP) {
    int s = 0;
    for (int c = 0; c < NCHUNK; c++) s += cnt[c * NEXP + t];
    tot[t] = s;
  }
  __syncthreads();
  if (t == 0) {
    int run = 0;
    for (int e = 0; e < NEXP; e++) { base[e] = run; run += tot[e]; }
  }
  __syncthreads();
  if (t < NEXP) {
    int run = base[t];
    for (int c = 0; c < NCHUNK; c++) { off[c * NEXP + t] = run; run += cnt[c * NEXP + t]; }
  }
}

// ---------------- sort step 3: ranks -> permutation ----------------
__global__ __launch_bounds__(64) void rank_kernel(
    const int* __restrict__ idx, const int* __restrict__ off,
    int* __restrict__ sortpos, int* __restrict__ orig, int* __restrict__ eidx) {
  if (threadIdx.x != 0) return;
  int c = blockIdx.x;
  int lc[NEXP];
#pragma unroll
  for (int e = 0; e < NEXP; e++) lc[e] = 0;
  for (int t = 0; t < CHUNK; t++) {
    int n = c * CHUNK + t;
    int e = idx[n];
    int dst = off[c * NEXP + e] + lc[e]++;
    sortpos[n] = dst;
    orig[dst] = n;
    eidx[dst] = e;
  }
}

// ---------------- permuted x -> bf16 (row-coalesced) ----------------
__global__ __launch_bounds__(256) void permute_x_kernel(
    const float* __restrict__ x, const int* __restrict__ sortpos,
    unsigned short* __restrict__ xb) {
  int wave = threadIdx.x >> 6, lane = threadIdx.x & 63;
  int n = blockIdx.x * 4 + wave;
  int dst = sortpos[n];
  const float* xr = x + (size_t)n * DDIM;
  unsigned short* xbr = xb + (size_t)dst * DDIM;
#pragma unroll
  for (int j = 0; j < 8; j++) {
    int d = j * 256 + lane * 4;
    floatx4 v = *(const floatx4*)(xr + d);
    ushortx4 s;
    s[0] = f2bf(v[0]); s[1] = f2bf(v[1]); s[2] = f2bf(v[2]); s[3] = f2bf(v[3]);
    *(ushortx4*)(xbr + d) = s;
  }
}

// ---------------- fp32 [Rr][Cc] -> bf16 [Cc][Rr] transpose ----------------
__global__ __launch_bounds__(256) void transpose_w_kernel(
    const float* __restrict__ in, unsigned short* __restrict__ out, int Rr, int Cc) {
  __shared__ float lds[32][33];
  int r0 = blockIdx.y * 32, c0 = blockIdx.x * 32;
  int tx = threadIdx.x & 31, ty = threadIdx.x >> 5;
#pragma unroll
  for (int k = 0; k < 4; k++) {
    int r = ty + k * 8;
    lds[r][tx] = in[(size_t)(r0 + r) * Cc + c0 + tx];
  }
  __syncthreads();
#pragma unroll
  for (int k = 0; k < 4; k++) {
    int cc = ty + k * 8;
    out[(size_t)(c0 + cc) * Rr + r0 + tx] = f2bf(lds[tx][cc]);
  }
}

// ---------------- pack A_gate/A_up -> aat[512][2048] bf16 (row = h*256+e*32+r) ----------------
__global__ __launch_bounds__(256) void pack_a_kernel(
    const float* __restrict__ Ag, const float* __restrict__ Au,
    unsigned short* __restrict__ aat) {
  int o = blockIdx.x * 256 + threadIdx.x;    // [0, 2^20)
  int h = o >> 19;
  int oo = o & ((1 << 19) - 1);
  int c = oo >> 11, d = oo & 2047;           // c in [0,256)
  int e = c >> 5, r = c & 31;
  const float* src = h ? Au : Ag;
  float v = src[(e << 16) + (d << 5) + r];   // A[e][d][r]
  aat[(size_t)(h * 256 + c) * DDIM + d] = f2bf(v);
}

// ---------------- B[e][R][I] fp32 -> Bt[e][I][R] bf16 ----------------
__global__ __launch_bounds__(256) void transpose_b_kernel(
    const float* __restrict__ Bg, const float* __restrict__ Bu,
    unsigned short* __restrict__ btg, unsigned short* __restrict__ btu) {
  __shared__ float lds[32][33];
  int i0 = blockIdx.x * 32, e = blockIdx.y;
  const float* in = blockIdx.z ? Bu : Bg;
  unsigned short* out = blockIdx.z ? btu : btg;
  int tx = threadIdx.x & 31, ty = threadIdx.x >> 5;
#pragma unroll
  for (int k = 0; k < 4; k++) {
    int r = ty + k * 8;
    lds[r][tx] = in[((size_t)e * RLORA + r) * IDIM + i0 + tx];
  }
  __syncthreads();
#pragma unroll
  for (int k = 0; k < 4; k++) {
    int ii = ty + k * 8;
    out[((size_t)e * IDIM + i0 + ii) * RLORA + tx] = f2bf(lds[tx][ii]);
  }
}

// ---------------- Tsel[8192][64]: per-token own-expert x@[A_gate|A_up] ----------------
__global__ __launch_bounds__(256) void gemm_tsel_kernel(
    const unsigned short* __restrict__ xb, const unsigned short* __restrict__ aat,
    const int* __restrict__ eidx, unsigned short* __restrict__ Tsel) {
  __shared__ __align__(16) unsigned short sA[4096], sB[2048];
  __shared__ int es_s[128];
  const int row0 = blockIdx.x * 128;
  const int tid = threadIdx.x;
  const int wave = tid >> 6, lane = tid & 63;
  const int wr = wave >> 1, wc = wave & 1;
  const int q = lane >> 4, m16 = lane & 15;
  if (tid < 128) es_s[tid] = eidx[row0 + tid];
  __syncthreads();
  const int emin = es_s[0], emax = es_s[127];
  int erow[4];
#pragma unroll
  for (int m = 0; m < 4; m++) erow[m] = es_s[wr * 64 + m * 16 + m16];
  floatx4 acc[8];
#pragma unroll
  for (int i = 0; i < 8; i++)
#pragma unroll
    for (int j = 0; j < 4; j++) acc[i][j] = 0.f;
  short8 zero;
#pragma unroll
  for (int i = 0; i < 8; i++) zero[i] = 0;
  for (int ee = emin; ee <= emax; ee++) {
    for (int k0 = 0; k0 < DDIM; k0 += 32) {
      __syncthreads();
#pragma unroll
      for (int rr = 0; rr < 2; rr++) {
        int e = tid * 8 + rr * 2048;
        int r = e >> 5, kk = e & 31;
        gload_lds16(xb + (size_t)(row0 + r) * DDIM + (k0 + kk), sA + e);
      }
      {
        int e2 = tid * 8;
        int c = e2 >> 5, kk = e2 & 31;
        int srow = (c < 32) ? (ee * 32 + c) : (256 + ee * 32 + (c - 32));
        gload_lds16(aat + (size_t)srow * DDIM + (k0 + kk), sB + e2);
      }
      __syncthreads();
      short8 a[4], b[2];
#pragma unroll
      for (int m = 0; m < 4; m++) {
        short8 av = *(const short8*)(sA + (wr * 64 + m * 16 + m16) * 32 + q * 8);
        a[m] = (erow[m] == ee) ? av : zero;
      }
#pragma unroll
      for (int n = 0; n < 2; n++)
        b[n] = *(const short8*)(sB + (wc * 32 + n * 16 + m16) * 32 + q * 8);
#pragma unroll
      for (int m = 0; m < 4; m++)
#pragma unroll
        for (int n = 0; n < 2; n++)
          acc[m * 2 + n] = __builtin_amdgcn_mfma_f32_16x16x32_bf16(a[m], b[n], acc[m * 2 + n], 0, 0, 0);
    }
  }
#pragma unroll
  for (int m = 0; m < 4; m++)
#pragma unroll
    for (int n = 0; n < 2; n++)
#pragma unroll
      for (int r = 0; r < 4; r++) {
        int grow = row0 + wr * 64 + m * 16 + q * 4 + r;
        int gcol = wc * 32 + n * 16 + m16;
        Tsel[(size_t)grow * 64 + gcol] = f2bf(acc[m * 2 + n][r]);
      }
}

// ---------------- fused gate+up GEMM, 128x64 tile per output ----------------
// accg[8]+accu[8] = 64 AGPR (R3 register profile, 3 waves/SIMD). x staged once
// for both outputs; shared LoRA epilogue; SwiGLU in registers; writes h only.
__global__ __launch_bounds__(256, 3) void gemm_gateup_kernel(
    const unsigned short* __restrict__ xb, const unsigned short* __restrict__ wgt,
    const unsigned short* __restrict__ wut, const unsigned short* __restrict__ Tsel,
    const unsigned short* __restrict__ btg, const unsigned short* __restrict__ btu,
    const int* __restrict__ eidx, unsigned short* __restrict__ hbuf) {
  __shared__ __align__(16) unsigned short smem[12288];  // 24 KB
  __shared__ int es_s[128];
  unsigned short* sA  = smem;          // main: 128x32 x-tile
  unsigned short* sBg = smem + 4096;   // main: 64x32 Wg-tile
  unsigned short* sBu = smem + 6144;   // main: 64x32 Wu-tile
  unsigned short* sTg = smem;          // epi: 128x32 Tsel gate half
  unsigned short* sTu = smem + 4096;   // epi: 128x32 Tsel up half
  unsigned short* sbg = smem + 8192;   // epi: 64x32 B_gate tile
  unsigned short* sbu = smem + 10240;  // epi: 64x32 B_up tile

  floatx4 accg[8], accu[8];
#pragma unroll
  for (int i = 0; i < 8; i++)
#pragma unroll
    for (int j = 0; j < 4; j++) { accg[i][j] = 0.f; accu[i][j] = 0.f; }

  // XCD swizzle: 6144 blocks; xcd band = 12 col-tiles, iterate 4-col subgroups
  // so Wg+Wu subgroup (2.1 MB) stays L2-resident across the 64-row sweep.
  int lin = blockIdx.x;
  int xcd = lin & 7, slot = lin >> 3;        // slot in [0,768)
  int grp = slot >> 8, sub = slot & 255;     // grp 0..2, sub 0..255
  int bx = xcd * 12 + grp * 4 + (sub & 3);   // col tile [0,96)
  int by = sub >> 2;                         // row tile [0,64)
  const int row0 = by * 128, col0 = bx * 64;

  const int tid = threadIdx.x;
  const int wave = tid >> 6, lane = tid & 63;
  const int wr = wave >> 1, wc = wave & 1;
  const int q = lane >> 4, m16 = lane & 15;

  // ---- main K loop over D ----
  for (int k0 = 0; k0 < DDIM; k0 += 32) {
    __syncthreads();
#pragma unroll
    for (int rr = 0; rr < 2; rr++) {
      int e = tid * 8 + rr * 2048;
      int r = e >> 5, kk = e & 31;
      gload_lds16(xb + (size_t)(row0 + r) * DDIM + (k0 + kk), sA + e);
    }
    {
      int e2 = tid * 8;
      int c = e2 >> 5, kk = e2 & 31;
      gload_lds16(wgt + (size_t)(col0 + c) * DDIM + (k0 + kk), sBg + e2);
      gload_lds16(wut + (size_t)(col0 + c) * DDIM + (k0 + kk), sBu + e2);
    }
    __syncthreads();
    short8 a[4], bg[2], bu[2];
#pragma unroll
    for (int m = 0; m < 4; m++)
      a[m] = *(const short8*)(sA + (wr * 64 + m * 16 + m16) * 32 + q * 8);
#pragma unroll
    for (int n = 0; n < 2; n++) {
      bg[n] = *(const short8*)(sBg + (wc * 32 + n * 16 + m16) * 32 + q * 8);
      bu[n] = *(const short8*)(sBu + (wc * 32 + n * 16 + m16) * 32 + q * 8);
    }
#pragma unroll
    for (int m = 0; m < 4; m++)
#pragma unroll
      for (int n = 0; n < 2; n++) {
        accg[m * 2 + n] = __builtin_amdgcn_mfma_f32_16x16x32_bf16(a[m], bg[n], accg[m * 2 + n], 0, 0, 0);
        accu[m * 2 + n] = __builtin_amdgcn_mfma_f32_16x16x32_bf16(a[m], bu[n], accu[m * 2 + n], 0, 0, 0);
      }
  }

  // ---- shared LoRA epilogue ----
  __syncthreads();   // main-loop frag reads done before sTg/sTu overwrite sA
  if (tid < 128) es_s[tid] = eidx[row0 + tid];
#pragma unroll
  for (int rr = 0; rr < 2; rr++) {
    int e = tid * 8 + rr * 2048;
    int r = e >> 5, kk = e & 31;
    *(floatx4*)(sTg + e) = *(const floatx4*)(Tsel + (size_t)(row0 + r) * 64 + kk);
    *(floatx4*)(sTu + e) = *(const floatx4*)(Tsel + (size_t)(row0 + r) * 64 + 32 + kk);
  }
  __syncthreads();
  const int emin = es_s[0], emax = es_s[127];
  int erow[4];
#pragma unroll
  for (int m = 0; m < 4; m++) erow[m] = es_s[wr * 64 + m * 16 + m16];
  short8 zero;
#pragma unroll
  for (int i = 0; i < 8; i++) zero[i] = 0;
  for (int ee = emin; ee <= emax; ee++) {
    __syncthreads();   // prior-iter frag reads done before restaging b tiles
    {
      int e2 = tid * 8;
      int c = e2 >> 5, kk = e2 & 31;
      *(floatx4*)(sbg + e2) = *(const floatx4*)(btg + ((size_t)ee * IDIM + col0 + c) * RLORA + kk);
      *(floatx4*)(sbu + e2) = *(const floatx4*)(btu + ((size_t)ee * IDIM + col0 + c) * RLORA + kk);
    }
    __syncthreads();
    short8 bg[2], bu[2], tg[4], tu[4];
#pragma unroll
    for (int n = 0; n < 2; n++) {
      bg[n] = *(const short8*)(sbg + (wc * 32 + n * 16 + m16) * 32 + q * 8);
      bu[n] = *(const short8*)(sbu + (wc * 32 + n * 16 + m16) * 32 + q * 8);
    }
#pragma unroll
    for (int m = 0; m < 4; m++) {
      int rloc = wr * 64 + m * 16 + m16;
      tg[m] = (erow[m] == ee) ? *(const short8*)(sTg + rloc * 32 + q * 8) : zero;
      tu[m] = (erow[m] == ee) ? *(const short8*)(sTu + rloc * 32 + q * 8) : zero;
    }
#pragma unroll
    for (int m = 0; m < 4; m++)
#pragma unroll
      for (int n = 0; n < 2; n++) {
        accg[m * 2 + n] = __builtin_amdgcn_mfma_f32_16x16x32_bf16(tg[m], bg[n], accg[m * 2 + n], 0, 0, 0);
        accu[m * 2 + n] = __builtin_amdgcn_mfma_f32_16x16x32_bf16(tu[m], bu[n], accu[m * 2 + n], 0, 0, 0);
      }
  }

  // ---- SwiGLU in registers, write h only ----
#pragma unroll
  for (int m = 0; m < 4; m++)
#pragma unroll
    for (int n = 0; n < 2; n++)
#pragma unroll
      for (int r = 0; r < 4; r++) {
        int grow = row0 + wr * 64 + m * 16 + q * 4 + r;
        int gcol = col0 + wc * 32 + n * 16 + m16;
        float gv = accg[m * 2 + n][r];
        float hv = gv / (1.f + __expf(-gv)) * accu[m * 2 + n][r];
        hbuf[(size_t)grow * IDIM + gcol] = f2bf(hv);
      }
}

// ---------------- shared GEMM main loop (down) ----------------
__device__ __forceinline__ void mm_main(const unsigned short* __restrict__ Ab,
                                        const unsigned short* __restrict__ Bb,
                                        int K, int row0, int col0,
                                        unsigned short* sA, unsigned short* sB,
                                        floatx4* acc) {
  const int tid = threadIdx.x;
  const int wave = tid >> 6, lane = tid & 63;
  const int wr = wave >> 1, wc = wave & 1;
  const int q = lane >> 4, m16 = lane & 15;
  for (int k0 = 0; k0 < K; k0 += 32) {
    __syncthreads();
#pragma unroll
    for (int rr = 0; rr < 2; rr++) {
      int e = tid * 8 + rr * 2048;
      int r = e >> 5, kk = e & 31;
      gload_lds16(Ab + (size_t)(row0 + r) * K + (k0 + kk), sA + e);
      gload_lds16(Bb + (size_t)(col0 + r) * K + (k0 + kk), sB + e);
    }
    __syncthreads();
    short8 a[4], b[4];
#pragma unroll
    for (int m = 0; m < 4; m++)
      a[m] = *(const short8*)(sA + (wr * 64 + m * 16 + m16) * 32 + q * 8);
#pragma unroll
    for (int n = 0; n < 4; n++)
      b[n] = *(const short8*)(sB + (wc * 64 + n * 16 + m16) * 32 + q * 8);
#pragma unroll
    for (int m = 0; m < 4; m++)
#pragma unroll
      for (int n = 0; n < 4; n++)
        acc[m * 4 + n] = __builtin_amdgcn_mfma_f32_16x16x32_bf16(a[m], b[n], acc[m * 4 + n], 0, 0, 0);
  }
}

__global__ __launch_bounds__(256) void gemm_down_kernel(
    const unsigned short* __restrict__ hb, const unsigned short* __restrict__ wdt,
    const int* __restrict__ orig, float* __restrict__ out) {
  __shared__ __align__(16) unsigned short sA[4096], sB[4096];
  floatx4 acc[16];
#pragma unroll
  for (int i = 0; i < 16; i++)
#pragma unroll
    for (int j = 0; j < 4; j++) acc[i][j] = 0.f;
  int lin = blockIdx.x;
  int xcd = lin & 7, slot = lin >> 3;      // slot in [0,128)
  int bx = xcd * 2 + (slot & 1);           // col tile [0,16)
  int by = slot >> 1;                      // row tile [0,64)
  int row0 = by * 128, col0 = bx * 128;
  mm_main(hb, wdt, IDIM, row0, col0, sA, sB, acc);
  const int wave = threadIdx.x >> 6, lane = threadIdx.x & 63;
  const int wr = wave >> 1, wc = wave & 1;
  const int q = lane >> 4, m16 = lane & 15;
#pragma unroll
  for (int m = 0; m < 4; m++)
#pragma unroll
    for (int n = 0; n < 4; n++)
#pragma unroll
      for (int r = 0; r < 4; r++) {
        int grow = row0 + wr * 64 + m * 16 + q * 4 + r;
        int orow = orig[grow];
        int gcol = col0 + wc * 64 + n * 16 + m16;
        out[(size_t)orow * DDIM + gcol] = acc[m * 4 + n][r];
      }
}

extern "C" void kernel_launch(void* const* d_in, const int* in_sizes, int n_in,
                              void* d_out, int out_size, void* d_ws, size_t ws_size,
                              hipStream_t stream) {
  const float* x  = (const float*)d_in[0];
  const float* rw = (const float*)d_in[1];
  const float* Ag = (const float*)d_in[2];
  const float* Bg = (const float*)d_in[3];
  const float* Au = (const float*)d_in[4];
  const float* Bu = (const float*)d_in[5];
  const float* Wg = (const float*)d_in[6];
  const float* Wu = (const float*)d_in[7];
  const float* Wd = (const float*)d_in[8];
  float* out = (float*)d_out;
  float* logits = out + (size_t)N_TOK * DDIM;

  char* ws = (char*)d_ws;
  size_t off = 0;
  auto alloc = [&](size_t bytes) {
    char* p = ws + off;
    off += (bytes + 255) & ~(size_t)255;
    return p;
  };
  unsigned short* xb  = (unsigned short*)alloc((size_t)N_TOK * DDIM * 2);
  unsigned short* wgt = (unsigned short*)alloc((size_t)IDIM * DDIM * 2);
  unsigned short* wut = (unsigned short*)alloc((size_t)IDIM * DDIM * 2);
  unsigned short* wdt = (unsigned short*)alloc((size_t)DDIM * IDIM * 2);
  unsigned short* aat = (unsigned short*)alloc((size_t)512 * DDIM * 2);
  unsigned short* btg = (unsigned short*)alloc((size_t)NEXP * IDIM * RLORA * 2);
  unsigned short* btu = (unsigned short*)alloc((size_t)NEXP * IDIM * RLORA * 2);
  unsigned short* Tsel= (unsigned short*)alloc((size_t)N_TOK * 64 * 2);
  unsigned short* hbuf= (unsigned short*)alloc((size_t)N_TOK * IDIM * 2);
  int* idx     = (int*)alloc((size_t)N_TOK * 4);
  int* sortpos = (int*)alloc((size_t)N_TOK * 4);
  int* orig    = (int*)alloc((size_t)N_TOK * 4);
  int* eidx    = (int*)alloc((size_t)N_TOK * 4);
  int* cnt     = (int*)alloc((size_t)NCHUNK * NEXP * 4);
  int* offb    = (int*)alloc((size_t)NCHUNK * NEXP * 4);

  router_kernel<<<N_TOK / 4, 256, 0, stream>>>(x, rw, logits, idx);
  count_kernel<<<NCHUNK, 128, 0, stream>>>(idx, cnt);
  scan_kernel<<<1, 64, 0, stream>>>(cnt, offb);
  rank_kernel<<<NCHUNK, 64, 0, stream>>>(idx, offb, sortpos, orig, eidx);
  permute_x_kernel<<<N_TOK / 4, 256, 0, stream>>>(x, sortpos, xb);
  transpose_w_kernel<<<dim3(IDIM / 32, DDIM / 32), 256, 0, stream>>>(Wg, wgt, DDIM, IDIM);
  transpose_w_kernel<<<dim3(IDIM / 32, DDIM / 32), 256, 0, stream>>>(Wu, wut, DDIM, IDIM);
  transpose_w_kernel<<<dim3(DDIM / 32, IDIM / 32), 256, 0, stream>>>(Wd, wdt, IDIM, DDIM);
  pack_a_kernel<<<4096, 256, 0, stream>>>(Ag, Au, aat);
  transpose_b_kernel<<<dim3(IDIM / 32, NEXP, 2), 256, 0, stream>>>(Bg, Bu, btg, btu);
  gemm_tsel_kernel<<<N_TOK / 128, 256, 0, stream>>>(xb, aat, eidx, Tsel);
  gemm_gateup_kernel<<<(IDIM / 64) * (N_TOK / 128), 256, 0, stream>>>(
      xb, wgt, wut, Tsel, btg, btu, eidx, hbuf);
  gemm_down_kernel<<<(DDIM / 128) * (N_TOK / 128), 256, 0, stream>>>(hbuf, wdt, orig, out);
}